// Round 2
// baseline (471.431 us; speedup 1.0000x reference)
//
#include <hip/hip_runtime.h>

#define DEVINL __device__ __forceinline__

typedef __attribute__((ext_vector_type(8))) __bf16 bf16x8;
typedef __attribute__((ext_vector_type(4))) __bf16 bf16x4;
typedef __attribute__((ext_vector_type(4))) float f32x4;

// D = A(16x32) * B(32x16) + C, bf16 inputs, fp32 accum.
// A: m=lane&15, k=(lane>>4)*8+j ; B: n=lane&15, k=(lane>>4)*8+j
// C/D: col=lane&15, row=(lane>>4)*4+reg   [m89/m120-verified]
DEVINL f32x4 mfma16(bf16x8 a, bf16x8 b, f32x4 c) {
  return __builtin_amdgcn_mfma_f32_16x16x32_bf16(a, b, c, 0, 0, 0);
}

// Fragment of W^T: value[j] = W[kb+j][n]  (W stored (in,out), row-major 128x128)
DEVINL bf16x8 loadWfrag(const float* __restrict__ W, int kb, int n) {
  bf16x8 f;
#pragma unroll
  for (int j = 0; j < 8; ++j) f[j] = (__bf16)W[(kb + j) * 128 + n];
  return f;
}

// ---------------------------------------------------------------------------
// Kernel A: per (seq, 256-token chunk): Q,K,V projections (bf16 MFMA),
// elu+1 on K,Q; Q -> global ws (bf16); K^T,V^T -> 32-token LDS strips
// (wave-private rows, in-wave DS ordering -> no barrier, R1-validated);
// KtV (per-head 32x32) + ksum accumulated in registers, flushed with PLAIN
// coalesced stores to a per-block partial slot (NO atomics -- R1 showed
// device-scope atomicAdd RMW traffic exploded to 190+ MB HBM writes).
// LDS 37888 B -> 4 blocks/CU; grid 1024 = 4 blocks/CU exactly.
// ---------------------------------------------------------------------------
__global__ __launch_bounds__(256, 4)
void qkv_ktv_kernel(const float* __restrict__ X,
                    const float* __restrict__ Wq, const float* __restrict__ bq,
                    const float* __restrict__ Wk, const float* __restrict__ bk,
                    const float* __restrict__ Wv, const float* __restrict__ bv,
                    __bf16* __restrict__ Qout,
                    float* __restrict__ ktvP, float* __restrict__ ksumP)
{
  __shared__ __bf16 Xs[64 * 136];   // 17408 B: [tok][e], pad 8
  __shared__ __bf16 Kt[128 * 40];   // 10240 B: [e][tok-in-32-strip], pad 8
  __shared__ __bf16 Vt[128 * 40];   // 10240 B

  const int tid  = threadIdx.x;
  const int lane = tid & 63;
  const int w    = tid >> 6;       // wave 0..3 (= head for KtV)
  const int l15  = lane & 15;
  const int quad = lane >> 4;      // 0..3
  const int s     = blockIdx.x >> 3;   // sequence 0..127
  const int chunk = blockIdx.x & 7;    // 256-token chunk
  const int tokc0 = chunk * 256;
  const float* Xc = X + ((size_t)s * 2048 + tokc0) * 128;

  // Register-resident weight fragments. Wave w owns out-dims [32w, 32w+32).
  bf16x8 wkF[2][4], wvF[2][4], wqF[2][4];
#pragma unroll
  for (int nt = 0; nt < 2; ++nt) {
    const int n = w * 32 + nt * 16 + l15;
#pragma unroll
    for (int kk = 0; kk < 4; ++kk) {
      const int kb = kk * 32 + quad * 8;
      wkF[nt][kk] = loadWfrag(Wk, kb, n);
      wvF[nt][kk] = loadWfrag(Wv, kb, n);
      wqF[nt][kk] = loadWfrag(Wq, kb, n);  // used as A-operand (orientation 2)
    }
  }
  float bkr[2], bvr[2], bqr[2][4];
#pragma unroll
  for (int nt = 0; nt < 2; ++nt) {
    bkr[nt] = bk[w * 32 + nt * 16 + l15];
    bvr[nt] = bv[w * 32 + nt * 16 + l15];
#pragma unroll
    for (int r = 0; r < 4; ++r)
      bqr[nt][r] = bq[w * 32 + nt * 16 + quad * 4 + r];
  }

  f32x4 accT[2][2] = {};          // per-head KtV accumulators [dt][et]
  float ksumAcc[2] = {0.f, 0.f};  // per-lane partial ksum (fixed e per nt)

  for (int t = 0; t < 4; ++t) {
    const float* Xtile = Xc + t * 64 * 128;
    __syncthreads();  // previous tile fully consumed Xs
    // --- stage X tile (fp32 global -> bf16 LDS), coalesced float4 ---
#pragma unroll
    for (int i = 0; i < 8; ++i) {
      const int flat = tid + i * 256;          // 2048 float4-chunks
      const int row = flat >> 5;
      const int c4  = (flat & 31) * 4;
      const float4 v = *(const float4*)(Xtile + row * 128 + c4);
      bf16x4 b4;
      b4[0] = (__bf16)v.x; b4[1] = (__bf16)v.y;
      b4[2] = (__bf16)v.z; b4[3] = (__bf16)v.w;
      *(bf16x4*)(&Xs[row * 136 + c4]) = b4;
    }
    __syncthreads();  // Xs ready

    // --- K,V projections + KtV, per 32-token half-tile ---
#pragma unroll
    for (int half = 0; half < 2; ++half) {
#pragma unroll
      for (int mt2 = 0; mt2 < 2; ++mt2) {
        const int mt = half * 2 + mt2;
        f32x4 aK[2] = {}, aV[2] = {};
#pragma unroll
        for (int kk = 0; kk < 4; ++kk) {
          const bf16x8 ax = *(const bf16x8*)(&Xs[(mt * 16 + l15) * 136 + kk * 32 + quad * 8]);
          aK[0] = mfma16(ax, wkF[0][kk], aK[0]);
          aK[1] = mfma16(ax, wkF[1][kk], aK[1]);
          aV[0] = mfma16(ax, wvF[0][kk], aV[0]);
          aV[1] = mfma16(ax, wvF[1][kk], aV[1]);
        }
        // epilogue: bias (+ elu+1 for K); write transposed into the strip.
#pragma unroll
        for (int nt = 0; nt < 2; ++nt) {
          const int e    = w * 32 + nt * 16 + l15;
          const int tokb = mt2 * 16 + quad * 4;   // token within 32-strip
          bf16x4 kq, vq;
          float ks = 0.f;
#pragma unroll
          for (int r = 0; r < 4; ++r) {
            float kv = aK[nt][r] + bkr[nt];
            kv = (kv > 0.f) ? (kv + 1.f) : __expf(kv);   // elu(x)+1
            ks += kv;
            kq[r] = (__bf16)kv;
            vq[r] = (__bf16)(aV[nt][r] + bvr[nt]);
          }
          ksumAcc[nt] += ks;
          *(bf16x4*)(&Kt[e * 40 + tokb]) = kq;
          *(bf16x4*)(&Vt[e * 40 + tokb]) = vq;
        }
      }
      // KtV on this 32-token strip. Wave reads only rows it wrote itself;
      // a wave's DS ops execute in order -> no barrier (R1-validated).
      bf16x8 aF[2], bF[2];
#pragma unroll
      for (int dt = 0; dt < 2; ++dt)
        aF[dt] = *(const bf16x8*)(&Kt[(w * 32 + dt * 16 + l15) * 40 + quad * 8]);
#pragma unroll
      for (int et = 0; et < 2; ++et)
        bF[et] = *(const bf16x8*)(&Vt[(w * 32 + et * 16 + l15) * 40 + quad * 8]);
#pragma unroll
      for (int dt = 0; dt < 2; ++dt)
#pragma unroll
        for (int et = 0; et < 2; ++et)
          accT[dt][et] = mfma16(aF[dt], bF[et], accT[dt][et]);
    }

    // --- Q projection, orientation 2: D[e][tok] = W^T @ X^T ---
    // C/D lane holds 4 consecutive e at fixed token -> contiguous global store.
#pragma unroll
    for (int ntq = 0; ntq < 4; ++ntq) {
      f32x4 aQ[2] = {};
#pragma unroll
      for (int kk = 0; kk < 4; ++kk) {
        const bf16x8 bx = *(const bf16x8*)(&Xs[(ntq * 16 + l15) * 136 + kk * 32 + quad * 8]);
        aQ[0] = mfma16(wqF[0][kk], bx, aQ[0]);
        aQ[1] = mfma16(wqF[1][kk], bx, aQ[1]);
      }
      const int tok = tokc0 + t * 64 + ntq * 16 + l15;
      __bf16* qrow = Qout + ((size_t)s * 2048 + tok) * 128;
#pragma unroll
      for (int mt = 0; mt < 2; ++mt) {
        bf16x4 qq;
#pragma unroll
        for (int r = 0; r < 4; ++r) {
          float qv = aQ[mt][r] + bqr[mt][r];
          qv = (qv > 0.f) ? (qv + 1.f) : __expf(qv);
          qq[r] = (__bf16)qv;
        }
        *(bf16x4*)(qrow + w * 32 + mt * 16 + quad * 4) = qq;
      }
    }
  }

  // --- flush partials with PLAIN stores (no atomics, no memset needed) ---
  // ktvP[block][h][d][e'], ksumP[block][e]
  float* kp = ktvP + ((size_t)blockIdx.x * 4 + w) * 1024;
#pragma unroll
  for (int dt = 0; dt < 2; ++dt)
#pragma unroll
    for (int et = 0; et < 2; ++et)
#pragma unroll
      for (int r = 0; r < 4; ++r)
        kp[(dt * 16 + quad * 4 + r) * 32 + et * 16 + l15] = accT[dt][et][r];

#pragma unroll
  for (int nt = 0; nt < 2; ++nt) {
    float v2 = ksumAcc[nt];
    v2 += __shfl_down(v2, 32);
    v2 += __shfl_down(v2, 16);
    if (quad == 0)
      ksumP[(size_t)blockIdx.x * 128 + w * 32 + nt * 16 + l15] = v2;
  }
}

// ---------------------------------------------------------------------------
// Kernel B: preamble reduces the 8 chunk-partials of (s) directly into aKtv
// fragments + ksum8 registers (L3-hot).  Per tile: load bf16 Q; Z fully
// in-register from the SAME bq8 fragment GEMM2 consumes (8/32 q*ksum terms
// per lane, 2 shfl_xor finish the head-local dot -- no Z LDS, no barrier);
// GEMM2 (q @ KtV_h)*Z -> A2s; GEMM3 out = A2 @ Wo + bo.
// LDS 34816 B -> 4 blocks/CU; 3 barriers/tile.
// ---------------------------------------------------------------------------
__global__ __launch_bounds__(256, 4)
void attn_out_kernel(const __bf16* __restrict__ Qin,
                     const float* __restrict__ ktvP, const float* __restrict__ ksumP,
                     const float* __restrict__ Wo, const float* __restrict__ bo,
                     float* __restrict__ Out)
{
  __shared__ __bf16 Qs[64 * 136];
  __shared__ __bf16 A2s[64 * 136];

  const int tid  = threadIdx.x;
  const int lane = tid & 63;
  const int w    = tid >> 6;   // wave = head
  const int l15  = lane & 15;
  const int quad = lane >> 4;
  const int s     = blockIdx.x >> 3;
  const int chunk = blockIdx.x & 7;

  // --- reduce ktv partials -> orientation-2 A-frags: A[e'][d] = KtV[h][d][e']
  const float* kpBase = ktvP + ((size_t)s * 8 * 4 + w) * 1024;
  bf16x8 aKtv[2];
#pragma unroll
  for (int mt = 0; mt < 2; ++mt)
#pragma unroll
    for (int j = 0; j < 8; ++j) {
      float acc = 0.f;
#pragma unroll
      for (int c = 0; c < 8; ++c)
        acc += kpBase[(size_t)c * 4096 + (quad * 8 + j) * 32 + mt * 16 + l15];
      aKtv[mt][j] = (__bf16)acc;
    }
  // --- reduce ksum partials; lane needs e = w*32 + quad*8 + j ---
  float ksum8[8];
#pragma unroll
  for (int j = 0; j < 8; ++j) {
    float a = 0.f;
#pragma unroll
    for (int c = 0; c < 8; ++c)
      a += ksumP[((size_t)s * 8 + c) * 128 + w * 32 + quad * 8 + j];
    ksum8[j] = a;
  }

  bf16x8 woF[2][4];
  float bor[2];
#pragma unroll
  for (int nt = 0; nt < 2; ++nt) {
    const int n = w * 32 + nt * 16 + l15;
    bor[nt] = bo[n];
#pragma unroll
    for (int kk = 0; kk < 4; ++kk)
      woF[nt][kk] = loadWfrag(Wo, kk * 32 + quad * 8, n);
  }

  for (int t = 0; t < 4; ++t) {
    const int tok0 = chunk * 256 + t * 64;
    const __bf16* Qtile = Qin + ((size_t)s * 2048 + tok0) * 128;
    __syncthreads();  // prev iter done with Qs (GEMM2) and A2s (GEMM3)
#pragma unroll
    for (int i = 0; i < 4; ++i) {
      const int c = tid + i * 256;       // 1024 16B-chunks
      const int row = c >> 4, cc = (c & 15) * 8;
      *(bf16x8*)(&Qs[row * 136 + cc]) = *(const bf16x8*)(Qtile + row * 128 + cc);
    }
    __syncthreads();  // Qs ready

    // --- GEMM2 (orientation 2): D[e'][tok] = KtV_h-frag @ Q^T, scaled by Z.
    // Z in-register: lane's bq8 covers e = w*32+quad*8+{0..7} of token
    // ntq*16+l15; the 4 quads cover all 32 head dims.
#pragma unroll
    for (int ntq = 0; ntq < 4; ++ntq) {
      const bf16x8 bq8 = *(const bf16x8*)(&Qs[(ntq * 16 + l15) * 136 + w * 32 + quad * 8]);
      float dot = 0.f;
#pragma unroll
      for (int j = 0; j < 8; ++j) dot += (float)bq8[j] * ksum8[j];
      dot += __shfl_xor(dot, 16);
      dot += __shfl_xor(dot, 32);
      const float z = 1.f / (dot + 1e-6f);
      f32x4 acc[2] = {};
      acc[0] = mfma16(aKtv[0], bq8, acc[0]);
      acc[1] = mfma16(aKtv[1], bq8, acc[1]);
#pragma unroll
      for (int mt = 0; mt < 2; ++mt) {
        bf16x4 a4;
#pragma unroll
        for (int r = 0; r < 4; ++r) a4[r] = (__bf16)(acc[mt][r] * z);
        *(bf16x4*)(&A2s[(ntq * 16 + l15) * 136 + w * 32 + mt * 16 + quad * 4]) = a4;
      }
    }
    __syncthreads();  // A2 complete across all heads

    // --- GEMM3 (orientation 1): out[tok][n] = A2 @ Wo + bo ---
#pragma unroll
    for (int mt = 0; mt < 4; ++mt) {
      f32x4 acc[2] = {};
#pragma unroll
      for (int kk = 0; kk < 4; ++kk) {
        const bf16x8 aa = *(const bf16x8*)(&A2s[(mt * 16 + l15) * 136 + kk * 32 + quad * 8]);
        acc[0] = mfma16(aa, woF[0][kk], acc[0]);
        acc[1] = mfma16(aa, woF[1][kk], acc[1]);
      }
      const int tokb = tok0 + mt * 16 + quad * 4;
      float* orow = Out + ((size_t)s * 2048 + tokb) * 128;
#pragma unroll
      for (int nt = 0; nt < 2; ++nt) {
        const int n = w * 32 + nt * 16 + l15;
#pragma unroll
        for (int r = 0; r < 4; ++r)
          orow[(size_t)r * 128 + n] = acc[nt][r] + bor[nt];
      }
    }
  }
}

extern "C" void kernel_launch(void* const* d_in, const int* in_sizes, int n_in,
                              void* d_out, int out_size, void* d_ws, size_t ws_size,
                              hipStream_t stream) {
  const float* X  = (const float*)d_in[0];
  const float* Wq = (const float*)d_in[1];
  const float* bq = (const float*)d_in[2];
  const float* Wk = (const float*)d_in[3];
  const float* bk = (const float*)d_in[4];
  const float* Wv = (const float*)d_in[5];
  const float* bv = (const float*)d_in[6];
  const float* Wo = (const float*)d_in[7];
  const float* bo = (const float*)d_in[8];
  float* Out = (float*)d_out;

  // ws layout: Q bf16 [128][2048][128]           = 64 MiB
  //          | ktvP fp32 [1024 blocks][4][32][32] = 16 MiB
  //          | ksumP fp32 [1024 blocks][128]      = 512 KiB
  const size_t Q_BYTES    = (size_t)128 * 2048 * 128 * 2;
  const size_t KTVP_BYTES = (size_t)1024 * 4 * 1024 * 4;
  __bf16* Qws   = (__bf16*)d_ws;
  float* ktvP   = (float*)((char*)d_ws + Q_BYTES);
  float* ksumP  = (float*)((char*)d_ws + Q_BYTES + KTVP_BYTES);

  // No memset: every partial slot is fully written by kernel A before B reads.

  qkv_ktv_kernel<<<dim3(1024), dim3(256), 0, stream>>>(
      X, Wq, bq, Wk, bk, Wv, bv, Qws, ktvP, ksumP);
  attn_out_kernel<<<dim3(1024), dim3(256), 0, stream>>>(
      Qws, ktvP, ksumP, Wo, bo, Out);
}

// Round 3
// 310.501 us; speedup vs baseline: 1.5183x; 1.5183x over previous
//
#include <hip/hip_runtime.h>

#define DEVINL __device__ __forceinline__

typedef __attribute__((ext_vector_type(8))) __bf16 bf16x8;
typedef __attribute__((ext_vector_type(4))) __bf16 bf16x4;
typedef __attribute__((ext_vector_type(4))) float f32x4;

// D = A(16x32) * B(32x16) + C, bf16 inputs, fp32 accum.
// A: m=lane&15, k=(lane>>4)*8+j ; B: n=lane&15, k=(lane>>4)*8+j
// C/D: col=lane&15, row=(lane>>4)*4+reg   [m89/m120-verified]
DEVINL f32x4 mfma16(bf16x8 a, bf16x8 b, f32x4 c) {
  return __builtin_amdgcn_mfma_f32_16x16x32_bf16(a, b, c, 0, 0, 0);
}

// Fragment of W^T: value[j] = W[kb+j][n]  (W stored (in,out), row-major 128x128)
DEVINL bf16x8 loadWfrag(const float* __restrict__ W, int kb, int n) {
  bf16x8 f;
#pragma unroll
  for (int j = 0; j < 8; ++j) f[j] = (__bf16)W[(kb + j) * 128 + n];
  return f;
}

// ---------------------------------------------------------------------------
// Kernel A (R0 structure + latency fixes): per (seq, 512-token chunk):
// Q,K,V projections (bf16 MFMA), elu+1 on K,Q; Q -> global ws (bf16);
// K^T,V^T -> LDS; KtV (per-head 32x32) + ksum accumulated, atomicAdd to the
// small 2MiB ws slab (R0-proven cheap at 512 blocks; 1024-block variants
// exploded RMW traffic -- R1).
// Latency fixes vs R0:
//  - register double-buffer of the X tile: t+1's 8 float4 loads issue right
//    after the LDS write and stay in flight across the whole compute phase.
//  - tile-0 prefetch overlaps the scalar weight preamble.
//  - pre-KtV barrier removed (KtV reads only rows this wave wrote; a wave's
//    DS ops are in-order -- R2-validated). 2 barriers/tile instead of 3.
// ---------------------------------------------------------------------------
__global__ __launch_bounds__(256, 2)
void qkv_ktv_kernel(const float* __restrict__ X,
                    const float* __restrict__ Wq, const float* __restrict__ bq,
                    const float* __restrict__ Wk, const float* __restrict__ bk,
                    const float* __restrict__ Wv, const float* __restrict__ bv,
                    __bf16* __restrict__ Qout,
                    float* __restrict__ ktvWs, float* __restrict__ ksumWs)
{
  __shared__ __bf16 Xs[64 * 136];   // [tok][e], pad 8
  __shared__ __bf16 Kt[128 * 72];   // [e][tok] (transposed), pad 8
  __shared__ __bf16 Vt[128 * 72];

  const int tid  = threadIdx.x;
  const int lane = tid & 63;
  const int w    = tid >> 6;       // wave 0..3 (= head for KtV)
  const int l15  = lane & 15;
  const int quad = lane >> 4;      // 0..3
  const int s     = blockIdx.x >> 2;   // sequence 0..127
  const int chunk = blockIdx.x & 3;    // 512-token chunk
  const int tokc0 = chunk * 512;
  const float* Xseq = X + (size_t)s * 2048 * 128;

  // --- prefetch tile 0 BEFORE the weight preamble (overlaps scalar loads) ---
  float4 xst[8];
  {
    const float* Xt0 = Xseq + (size_t)tokc0 * 128;
#pragma unroll
    for (int i = 0; i < 8; ++i) {
      const int flat = tid + i * 256;
      xst[i] = *(const float4*)(Xt0 + (flat >> 5) * 128 + (flat & 31) * 4);
    }
  }

  // Register-resident weight fragments. Wave w owns out-dims [32w, 32w+32).
  bf16x8 wkF[2][4], wvF[2][4], wqF[2][4];
#pragma unroll
  for (int nt = 0; nt < 2; ++nt) {
    const int n = w * 32 + nt * 16 + l15;
#pragma unroll
    for (int kk = 0; kk < 4; ++kk) {
      const int kb = kk * 32 + quad * 8;
      wkF[nt][kk] = loadWfrag(Wk, kb, n);
      wvF[nt][kk] = loadWfrag(Wv, kb, n);
      wqF[nt][kk] = loadWfrag(Wq, kb, n);  // used as A-operand (orientation 2)
    }
  }
  float bkr[2], bvr[2], bqr[2][4];
#pragma unroll
  for (int nt = 0; nt < 2; ++nt) {
    bkr[nt] = bk[w * 32 + nt * 16 + l15];
    bvr[nt] = bv[w * 32 + nt * 16 + l15];
#pragma unroll
    for (int r = 0; r < 4; ++r)
      bqr[nt][r] = bq[w * 32 + nt * 16 + quad * 4 + r];
  }

  f32x4 accT[2][2] = {};          // per-head KtV accumulators [dt][et]
  float ksumAcc[2] = {0.f, 0.f};  // per-lane partial ksum (fixed e per nt)

  for (int t = 0; t < 8; ++t) {
    __syncthreads();  // previous tile fully consumed Xs
    // --- write staged regs -> LDS (bf16 convert) ---
#pragma unroll
    for (int i = 0; i < 8; ++i) {
      const int flat = tid + i * 256;
      const int row = flat >> 5;
      const int c4  = (flat & 31) * 4;
      bf16x4 b4;
      b4[0] = (__bf16)xst[i].x; b4[1] = (__bf16)xst[i].y;
      b4[2] = (__bf16)xst[i].z; b4[3] = (__bf16)xst[i].w;
      *(bf16x4*)(&Xs[row * 136 + c4]) = b4;
    }
    // --- issue next tile's loads; in flight across the entire compute phase ---
    if (t < 7) {
      const float* Xn = Xseq + (size_t)(tokc0 + (t + 1) * 64) * 128;
#pragma unroll
      for (int i = 0; i < 8; ++i) {
        const int flat = tid + i * 256;
        xst[i] = *(const float4*)(Xn + (flat >> 5) * 128 + (flat & 31) * 4);
      }
    }
    __syncthreads();  // Xs ready

    // --- K & V projections, orientation 1: D[tok][e] = X @ W ---
#pragma unroll
    for (int mt = 0; mt < 4; ++mt) {
      f32x4 aK[2] = {}, aV[2] = {};
#pragma unroll
      for (int kk = 0; kk < 4; ++kk) {
        const bf16x8 ax = *(const bf16x8*)(&Xs[(mt * 16 + l15) * 136 + kk * 32 + quad * 8]);
        aK[0] = mfma16(ax, wkF[0][kk], aK[0]);
        aK[1] = mfma16(ax, wkF[1][kk], aK[1]);
        aV[0] = mfma16(ax, wvF[0][kk], aV[0]);
        aV[1] = mfma16(ax, wvF[1][kk], aV[1]);
      }
      // epilogue: bias (+ elu+1 for K); write transposed to Kt/Vt.
#pragma unroll
      for (int nt = 0; nt < 2; ++nt) {
        const int e    = w * 32 + nt * 16 + l15;
        const int tokb = mt * 16 + quad * 4;
        bf16x4 kq, vq;
        float ks = 0.f;
#pragma unroll
        for (int r = 0; r < 4; ++r) {
          float kv = aK[nt][r] + bkr[nt];
          kv = (kv > 0.f) ? (kv + 1.f) : __expf(kv);   // elu(x)+1
          ks += kv;
          kq[r] = (__bf16)kv;
          vq[r] = (__bf16)(aV[nt][r] + bvr[nt]);
        }
        ksumAcc[nt] += ks;
        *(bf16x4*)(&Kt[e * 72 + tokb]) = kq;
        *(bf16x4*)(&Vt[e * 72 + tokb]) = vq;
      }
    }

    // --- KtV immediately (NO barrier): wave w = head w reads only the Kt/Vt
    // rows it wrote itself; a wave's DS ops execute in order. ---
#pragma unroll
    for (int kk = 0; kk < 2; ++kk) {
      bf16x8 aF[2], bF[2];
#pragma unroll
      for (int dt = 0; dt < 2; ++dt)
        aF[dt] = *(const bf16x8*)(&Kt[(w * 32 + dt * 16 + l15) * 72 + kk * 32 + quad * 8]);
#pragma unroll
      for (int et = 0; et < 2; ++et)
        bF[et] = *(const bf16x8*)(&Vt[(w * 32 + et * 16 + l15) * 72 + kk * 32 + quad * 8]);
#pragma unroll
      for (int dt = 0; dt < 2; ++dt)
#pragma unroll
        for (int et = 0; et < 2; ++et)
          accT[dt][et] = mfma16(aF[dt], bF[et], accT[dt][et]);
    }

    // --- Q projection, orientation 2: D[e][tok] = W^T @ X^T ---
#pragma unroll
    for (int ntq = 0; ntq < 4; ++ntq) {
      f32x4 aQ[2] = {};
#pragma unroll
      for (int kk = 0; kk < 4; ++kk) {
        const bf16x8 bx = *(const bf16x8*)(&Xs[(ntq * 16 + l15) * 136 + kk * 32 + quad * 8]);
        aQ[0] = mfma16(wqF[0][kk], bx, aQ[0]);
        aQ[1] = mfma16(wqF[1][kk], bx, aQ[1]);
      }
      const int tok = tokc0 + t * 64 + ntq * 16 + l15;
      __bf16* qrow = Qout + ((size_t)s * 2048 + tok) * 128;
#pragma unroll
      for (int mt = 0; mt < 2; ++mt) {
        bf16x4 qq;
#pragma unroll
        for (int r = 0; r < 4; ++r) {
          float qv = aQ[mt][r] + bqr[mt][r];
          qv = (qv > 0.f) ? (qv + 1.f) : __expf(qv);
          qq[r] = (__bf16)qv;
        }
        *(bf16x4*)(qrow + w * 32 + mt * 16 + quad * 4) = qq;
      }
    }
  }

  // --- flush partials: ktv[s][h][d][e], ksum[s][e] (fp32 atomics, small slab) ---
  float* ktvH = ktvWs + ((size_t)s * 4 + w) * 1024;
#pragma unroll
  for (int dt = 0; dt < 2; ++dt)
#pragma unroll
    for (int et = 0; et < 2; ++et)
#pragma unroll
      for (int r = 0; r < 4; ++r)
        atomicAdd(&ktvH[(dt * 16 + quad * 4 + r) * 32 + et * 16 + l15], accT[dt][et][r]);

#pragma unroll
  for (int nt = 0; nt < 2; ++nt) {
    float v2 = ksumAcc[nt];
    v2 += __shfl_down(v2, 32);
    v2 += __shfl_down(v2, 16);
    if (quad == 0)
      atomicAdd(&ksumWs[s * 128 + w * 32 + nt * 16 + l15], v2);
  }
}

// ---------------------------------------------------------------------------
// Kernel B: per (seq, 256-token chunk): load bf16 Q (register double-buffer);
// Z fully in-register (the SAME bq8 fragment GEMM2 consumes holds 8/32 of the
// q.ksum terms; shfl_xor 16/32 finish the head dot -- no Z LDS phase, no
// extra barrier); GEMM2 (q @ KtV_h)*Z -> A2s; GEMM3 in orientation 2 so the
// epilogue is 8 float4 stores per wave (full 64B-line coverage per store).
// LDS 34816 B -> 4 blocks/CU; 3 barriers/tile; ktvWs/ksumWs are the small
// atomically-reduced slabs (L2-hot).
// ---------------------------------------------------------------------------
__global__ __launch_bounds__(256, 4)
void attn_out_kernel(const __bf16* __restrict__ Qin,
                     const float* __restrict__ ktvWs, const float* __restrict__ ksumWs,
                     const float* __restrict__ Wo, const float* __restrict__ bo,
                     float* __restrict__ Out)
{
  __shared__ __bf16 Qs[64 * 136];
  __shared__ __bf16 A2s[64 * 136];

  const int tid  = threadIdx.x;
  const int lane = tid & 63;
  const int w    = tid >> 6;   // wave = head
  const int l15  = lane & 15;
  const int quad = lane >> 4;
  const int s     = blockIdx.x >> 3;
  const int chunk = blockIdx.x & 7;
  const __bf16* Qc = Qin + ((size_t)s * 2048 + chunk * 256) * 128;

  // --- prefetch Q tile 0 before the preamble ---
  bf16x8 qst[4];
#pragma unroll
  for (int i = 0; i < 4; ++i) {
    const int c = tid + i * 256;
    qst[i] = *(const bf16x8*)(Qc + (c >> 4) * 128 + (c & 15) * 8);
  }

  // KtV_h as orientation-2 A-fragments: A[e'][d] = KtV[h][d][e']
  const float* ktvH = ktvWs + ((size_t)s * 4 + w) * 1024;
  bf16x8 aKtv[2];
#pragma unroll
  for (int mt = 0; mt < 2; ++mt)
#pragma unroll
    for (int j = 0; j < 8; ++j)
      aKtv[mt][j] = (__bf16)ktvH[(quad * 8 + j) * 32 + mt * 16 + l15];

  // ksum for the in-register Z: lane needs e = w*32 + quad*8 + j
  float ksum8[8];
#pragma unroll
  for (int j = 0; j < 8; ++j)
    ksum8[j] = ksumWs[s * 128 + w * 32 + quad * 8 + j];

  // Wo fragments (A-operand for orientation-2 GEMM3) + per-lane bias
  bf16x8 woF[2][4];
  float borr[2][4];
#pragma unroll
  for (int nt = 0; nt < 2; ++nt) {
    const int n = w * 32 + nt * 16 + l15;
#pragma unroll
    for (int kk = 0; kk < 4; ++kk)
      woF[nt][kk] = loadWfrag(Wo, kk * 32 + quad * 8, n);
#pragma unroll
    for (int r = 0; r < 4; ++r)
      borr[nt][r] = bo[w * 32 + nt * 16 + quad * 4 + r];
  }

  for (int t = 0; t < 4; ++t) {
    const int tok0 = chunk * 256 + t * 64;
    __syncthreads();  // Qs (prev GEMM2) and A2s (prev GEMM3) fully consumed
    // --- write staged Q regs -> LDS; issue next tile's loads ---
#pragma unroll
    for (int i = 0; i < 4; ++i) {
      const int c = tid + i * 256;
      *(bf16x8*)(&Qs[(c >> 4) * 136 + (c & 15) * 8]) = qst[i];
    }
    if (t < 3) {
      const __bf16* Qn = Qc + (size_t)(t + 1) * 64 * 128;
#pragma unroll
      for (int i = 0; i < 4; ++i) {
        const int c = tid + i * 256;
        qst[i] = *(const bf16x8*)(Qn + (c >> 4) * 128 + (c & 15) * 8);
      }
    }
    __syncthreads();  // Qs ready

    // --- GEMM2 (orientation 2): D[e'][tok] = KtV_h-frag @ Q^T, scaled by Z.
    // Z in-register: lane's bq8 covers e = w*32+quad*8+{0..7} of token
    // ntq*16+l15; shfl_xor over the 4 quads completes the head-local dot.
#pragma unroll
    for (int ntq = 0; ntq < 4; ++ntq) {
      const bf16x8 bq8 = *(const bf16x8*)(&Qs[(ntq * 16 + l15) * 136 + w * 32 + quad * 8]);
      float dot = 0.f;
#pragma unroll
      for (int j = 0; j < 8; ++j) dot += (float)bq8[j] * ksum8[j];
      dot += __shfl_xor(dot, 16);
      dot += __shfl_xor(dot, 32);
      const float z = 1.f / (dot + 1e-6f);
      f32x4 acc[2] = {};
      acc[0] = mfma16(aKtv[0], bq8, acc[0]);
      acc[1] = mfma16(aKtv[1], bq8, acc[1]);
#pragma unroll
      for (int mt = 0; mt < 2; ++mt) {
        bf16x4 a4;
#pragma unroll
        for (int r = 0; r < 4; ++r) a4[r] = (__bf16)(acc[mt][r] * z);
        *(bf16x4*)(&A2s[(ntq * 16 + l15) * 136 + w * 32 + mt * 16 + quad * 4]) = a4;
      }
    }
    __syncthreads();  // A2 complete across all heads

    // --- GEMM3 (orientation 2): D[n][tok] = Wo^T-frag @ A2^T + bo.
    // Lane holds 4 consecutive n at fixed token -> one float4 store each. ---
#pragma unroll
    for (int ntq = 0; ntq < 4; ++ntq) {
      f32x4 acc[2] = {};
#pragma unroll
      for (int kk = 0; kk < 4; ++kk) {
        const bf16x8 a2f = *(const bf16x8*)(&A2s[(ntq * 16 + l15) * 136 + kk * 32 + quad * 8]);
        acc[0] = mfma16(woF[0][kk], a2f, acc[0]);
        acc[1] = mfma16(woF[1][kk], a2f, acc[1]);
      }
      const int tok = tok0 + ntq * 16 + l15;
      float* orow = Out + ((size_t)s * 2048 + tok) * 128;
#pragma unroll
      for (int nt = 0; nt < 2; ++nt) {
        float4 o4;
        o4.x = acc[nt][0] + borr[nt][0];
        o4.y = acc[nt][1] + borr[nt][1];
        o4.z = acc[nt][2] + borr[nt][2];
        o4.w = acc[nt][3] + borr[nt][3];
        *(float4*)(orow + w * 32 + nt * 16 + quad * 4) = o4;
      }
    }
  }
}

extern "C" void kernel_launch(void* const* d_in, const int* in_sizes, int n_in,
                              void* d_out, int out_size, void* d_ws, size_t ws_size,
                              hipStream_t stream) {
  const float* X  = (const float*)d_in[0];
  const float* Wq = (const float*)d_in[1];
  const float* bq = (const float*)d_in[2];
  const float* Wk = (const float*)d_in[3];
  const float* bk = (const float*)d_in[4];
  const float* Wv = (const float*)d_in[5];
  const float* bv = (const float*)d_in[6];
  const float* Wo = (const float*)d_in[7];
  const float* bo = (const float*)d_in[8];
  float* Out = (float*)d_out;

  // ws layout: Q bf16 [128][2048][128] | ktv fp32 [128][4][32][32] | ksum fp32 [128][128]
  const size_t Q_BYTES    = (size_t)128 * 2048 * 128 * 2;        // 64 MiB
  const size_t KTV_BYTES  = (size_t)128 * 4 * 32 * 32 * 4;       // 2 MiB
  const size_t KSUM_BYTES = (size_t)128 * 128 * 4;               // 64 KiB
  __bf16* Qws   = (__bf16*)d_ws;
  float* ktvWs  = (float*)((char*)d_ws + Q_BYTES);
  float* ksumWs = (float*)((char*)d_ws + Q_BYTES + KTV_BYTES);

  hipMemsetAsync((char*)d_ws + Q_BYTES, 0, KTV_BYTES + KSUM_BYTES, stream);

  qkv_ktv_kernel<<<dim3(512), dim3(256), 0, stream>>>(
      X, Wq, bq, Wk, bk, Wv, bv, Qws, ktvWs, ksumWs);
  attn_out_kernel<<<dim3(1024), dim3(256), 0, stream>>>(
      Qws, ktvWs, ksumWs, Wo, bo, Out);
}

// Round 5
// 290.381 us; speedup vs baseline: 1.6235x; 1.0693x over previous
//
#include <hip/hip_runtime.h>

#define DEVINL __device__ __forceinline__

typedef __attribute__((ext_vector_type(8))) __bf16 bf16x8;
typedef __attribute__((ext_vector_type(4))) __bf16 bf16x4;
typedef __attribute__((ext_vector_type(4))) float f32x4;

// D = A(16x32) * B(32x16) + C, bf16 inputs, fp32 accum.
// A: m=lane&15, k=(lane>>4)*8+j ; B: n=lane&15, k=(lane>>4)*8+j
// C/D: col=lane&15, row=(lane>>4)*4+reg   [m89/m120-verified]
DEVINL f32x4 mfma16(bf16x8 a, bf16x8 b, f32x4 c) {
  return __builtin_amdgcn_mfma_f32_16x16x32_bf16(a, b, c, 0, 0, 0);
}

// Fragment of W^T: value[j] = W[kb+j][n]  (W stored (in,out), row-major 128x128)
DEVINL bf16x8 loadWfrag(const float* __restrict__ W, int kb, int n) {
  bf16x8 f;
#pragma unroll
  for (int j = 0; j < 8; ++j) f[j] = (__bf16)W[(kb + j) * 128 + n];
  return f;
}

// ---------------------------------------------------------------------------
// Kernel A: per (seq, 512-token chunk): Q,K,V projections (bf16 MFMA),
// elu+1 on K,Q; Q -> global ws (bf16); K^T,V^T -> LDS; KtV (per-head 32x32)
// + ksum accumulated, atomicAdd to the small 2MiB slab.
// R4 fix: prefetch of tile t+1 is issued AFTER the "Xs ready" barrier.
// (The compiler emits s_waitcnt vmcnt(0) before every s_barrier; issuing the
// loads before the barrier -- as in R3 -- drains them immediately and exposes
// full HBM latency every tile. Issued after, they fly across the whole
// compute phase and the drain at the next tile's first barrier is free.)
// NOTE: keep __launch_bounds__(256,2). (256,3)/(256,4) spill the 96+ VGPRs of
// resident weight fragments to scratch (R1: VGPR=84, R2: VGPR=64, FETCH/WRITE
// exploded to 190-330 MB of spill traffic).
// ---------------------------------------------------------------------------
__global__ __launch_bounds__(256, 2)
void qkv_ktv_kernel(const float* __restrict__ X,
                    const float* __restrict__ Wq, const float* __restrict__ bq,
                    const float* __restrict__ Wk, const float* __restrict__ bk,
                    const float* __restrict__ Wv, const float* __restrict__ bv,
                    __bf16* __restrict__ Qout,
                    float* __restrict__ ktvWs, float* __restrict__ ksumWs)
{
  __shared__ __bf16 Xs[64 * 136];   // [tok][e], pad 8
  __shared__ __bf16 Kt[128 * 72];   // [e][tok] (transposed), pad 8
  __shared__ __bf16 Vt[128 * 72];

  const int tid  = threadIdx.x;
  const int lane = tid & 63;
  const int w    = tid >> 6;       // wave 0..3 (= head for KtV)
  const int l15  = lane & 15;
  const int quad = lane >> 4;      // 0..3
  const int s     = blockIdx.x >> 2;   // sequence 0..127
  const int chunk = blockIdx.x & 3;    // 512-token chunk
  const int tokc0 = chunk * 512;
  const float* Xseq = X + (size_t)s * 2048 * 128;

  // --- prefetch tile 0 BEFORE the weight preamble (overlaps scalar loads) ---
  float4 xst[8];
  {
    const float* Xt0 = Xseq + (size_t)tokc0 * 128;
#pragma unroll
    for (int i = 0; i < 8; ++i) {
      const int flat = tid + i * 256;
      xst[i] = *(const float4*)(Xt0 + (flat >> 5) * 128 + (flat & 31) * 4);
    }
  }

  // Register-resident weight fragments. Wave w owns out-dims [32w, 32w+32).
  bf16x8 wkF[2][4], wvF[2][4], wqF[2][4];
#pragma unroll
  for (int nt = 0; nt < 2; ++nt) {
    const int n = w * 32 + nt * 16 + l15;
#pragma unroll
    for (int kk = 0; kk < 4; ++kk) {
      const int kb = kk * 32 + quad * 8;
      wkF[nt][kk] = loadWfrag(Wk, kb, n);
      wvF[nt][kk] = loadWfrag(Wv, kb, n);
      wqF[nt][kk] = loadWfrag(Wq, kb, n);  // used as A-operand (orientation 2)
    }
  }
  float bkr[2], bvr[2], bqr[2][4];
#pragma unroll
  for (int nt = 0; nt < 2; ++nt) {
    bkr[nt] = bk[w * 32 + nt * 16 + l15];
    bvr[nt] = bv[w * 32 + nt * 16 + l15];
#pragma unroll
    for (int r = 0; r < 4; ++r)
      bqr[nt][r] = bq[w * 32 + nt * 16 + quad * 4 + r];
  }

  f32x4 accT[2][2] = {};          // per-head KtV accumulators [dt][et]
  float ksumAcc[2] = {0.f, 0.f};  // per-lane partial ksum (fixed e per nt)

  for (int t = 0; t < 8; ++t) {
    __syncthreads();  // previous tile fully consumed Xs
    // --- write staged regs -> LDS (bf16 convert) ---
#pragma unroll
    for (int i = 0; i < 8; ++i) {
      const int flat = tid + i * 256;
      const int row = flat >> 5;
      const int c4  = (flat & 31) * 4;
      bf16x4 b4;
      b4[0] = (__bf16)xst[i].x; b4[1] = (__bf16)xst[i].y;
      b4[2] = (__bf16)xst[i].z; b4[3] = (__bf16)xst[i].w;
      *(bf16x4*)(&Xs[row * 136 + c4]) = b4;
    }
    __syncthreads();  // Xs ready

    // --- R4: issue next tile's loads AFTER the barrier so no vmcnt(0) drain
    // touches them until the next tile's first barrier (full compute cover) ---
    if (t < 7) {
      const float* Xn = Xseq + (size_t)(tokc0 + (t + 1) * 64) * 128;
#pragma unroll
      for (int i = 0; i < 8; ++i) {
        const int flat = tid + i * 256;
        xst[i] = *(const float4*)(Xn + (flat >> 5) * 128 + (flat & 31) * 4);
      }
    }

    // --- K & V projections, orientation 1: D[tok][e] = X @ W ---
#pragma unroll
    for (int mt = 0; mt < 4; ++mt) {
      f32x4 aK[2] = {}, aV[2] = {};
#pragma unroll
      for (int kk = 0; kk < 4; ++kk) {
        const bf16x8 ax = *(const bf16x8*)(&Xs[(mt * 16 + l15) * 136 + kk * 32 + quad * 8]);
        aK[0] = mfma16(ax, wkF[0][kk], aK[0]);
        aK[1] = mfma16(ax, wkF[1][kk], aK[1]);
        aV[0] = mfma16(ax, wvF[0][kk], aV[0]);
        aV[1] = mfma16(ax, wvF[1][kk], aV[1]);
      }
      // epilogue: bias (+ elu+1 for K); write transposed to Kt/Vt.
#pragma unroll
      for (int nt = 0; nt < 2; ++nt) {
        const int e    = w * 32 + nt * 16 + l15;
        const int tokb = mt * 16 + quad * 4;
        bf16x4 kq, vq;
        float ks = 0.f;
#pragma unroll
        for (int r = 0; r < 4; ++r) {
          float kv = aK[nt][r] + bkr[nt];
          kv = (kv > 0.f) ? (kv + 1.f) : __expf(kv);   // elu(x)+1
          ks += kv;
          kq[r] = (__bf16)kv;
          vq[r] = (__bf16)(aV[nt][r] + bvr[nt]);
        }
        ksumAcc[nt] += ks;
        *(bf16x4*)(&Kt[e * 72 + tokb]) = kq;
        *(bf16x4*)(&Vt[e * 72 + tokb]) = vq;
      }
    }

    // --- KtV immediately (NO barrier): wave w = head w reads only the Kt/Vt
    // rows it wrote itself; a wave's DS ops execute in order. ---
#pragma unroll
    for (int kk = 0; kk < 2; ++kk) {
      bf16x8 aF[2], bF[2];
#pragma unroll
      for (int dt = 0; dt < 2; ++dt)
        aF[dt] = *(const bf16x8*)(&Kt[(w * 32 + dt * 16 + l15) * 72 + kk * 32 + quad * 8]);
#pragma unroll
      for (int et = 0; et < 2; ++et)
        bF[et] = *(const bf16x8*)(&Vt[(w * 32 + et * 16 + l15) * 72 + kk * 32 + quad * 8]);
#pragma unroll
      for (int dt = 0; dt < 2; ++dt)
#pragma unroll
        for (int et = 0; et < 2; ++et)
          accT[dt][et] = mfma16(aF[dt], bF[et], accT[dt][et]);
    }

    // --- Q projection, orientation 2: D[e][tok] = W^T @ X^T ---
#pragma unroll
    for (int ntq = 0; ntq < 4; ++ntq) {
      f32x4 aQ[2] = {};
#pragma unroll
      for (int kk = 0; kk < 4; ++kk) {
        const bf16x8 bx = *(const bf16x8*)(&Xs[(ntq * 16 + l15) * 136 + kk * 32 + quad * 8]);
        aQ[0] = mfma16(wqF[0][kk], bx, aQ[0]);
        aQ[1] = mfma16(wqF[1][kk], bx, aQ[1]);
      }
      const int tok = tokc0 + t * 64 + ntq * 16 + l15;
      __bf16* qrow = Qout + ((size_t)s * 2048 + tok) * 128;
#pragma unroll
      for (int mt = 0; mt < 2; ++mt) {
        bf16x4 qq;
#pragma unroll
        for (int r = 0; r < 4; ++r) {
          float qv = aQ[mt][r] + bqr[mt][r];
          qv = (qv > 0.f) ? (qv + 1.f) : __expf(qv);
          qq[r] = (__bf16)qv;
        }
        *(bf16x4*)(qrow + w * 32 + mt * 16 + quad * 4) = qq;
      }
    }
  }

  // --- flush partials: ktv[s][h][d][e], ksum[s][e] (fp32 atomics, small slab;
  // proven cheap at 512 blocks / 4 writers per line) ---
  float* ktvH = ktvWs + ((size_t)s * 4 + w) * 1024;
#pragma unroll
  for (int dt = 0; dt < 2; ++dt)
#pragma unroll
    for (int et = 0; et < 2; ++et)
#pragma unroll
      for (int r = 0; r < 4; ++r)
        atomicAdd(&ktvH[(dt * 16 + quad * 4 + r) * 32 + et * 16 + l15], accT[dt][et][r]);

#pragma unroll
  for (int nt = 0; nt < 2; ++nt) {
    float v2 = ksumAcc[nt];
    v2 += __shfl_down(v2, 32);
    v2 += __shfl_down(v2, 16);
    if (quad == 0)
      atomicAdd(&ksumWs[s * 128 + w * 32 + nt * 16 + l15], v2);
  }
}

// ---------------------------------------------------------------------------
// Kernel B (R4 rewrite): NO Qs LDS stage. GEMM2's B-fragment is a direct
// 16B global load of Q[tok][head-e-chunk] (L2/L3-hot, 64B-contiguous per
// quad group). Z fully in-register from the same fragment (8/32 q.ksum terms
// per lane; shfl_xor 16/32 finish the head dot). GEMM2 -> A2s; GEMM3
// (orientation 2, float4 coalesced stores). 2 barriers/tile. Next-tile qf
// loads are issued at the start of GEMM3 so ~32 MFMA + stores cover their
// latency before the end-of-tile barrier drains them.
// LDS = A2s only (17408 B). VGPR ~106 -> fits (256,4) without spill.
// ---------------------------------------------------------------------------
__global__ __launch_bounds__(256, 4)
void attn_out_kernel(const __bf16* __restrict__ Qin,
                     const float* __restrict__ ktvWs, const float* __restrict__ ksumWs,
                     const float* __restrict__ Wo, const float* __restrict__ bo,
                     float* __restrict__ Out)
{
  __shared__ __bf16 A2s[64 * 136];

  const int tid  = threadIdx.x;
  const int lane = tid & 63;
  const int w    = tid >> 6;   // wave = head
  const int l15  = lane & 15;
  const int quad = lane >> 4;
  const int s     = blockIdx.x >> 3;
  const int chunk = blockIdx.x & 7;
  const __bf16* Qc = Qin + ((size_t)s * 2048 + chunk * 256) * 128;

  // --- prefetch qf for tile 0 BEFORE the preamble (overlaps scalar loads) ---
  bf16x8 qf[4];
#pragma unroll
  for (int ntq = 0; ntq < 4; ++ntq)
    qf[ntq] = *(const bf16x8*)(Qc + (size_t)(ntq * 16 + l15) * 128 + w * 32 + quad * 8);

  // KtV_h as orientation-2 A-fragments: A[e'][d] = KtV[h][d][e']
  const float* ktvH = ktvWs + ((size_t)s * 4 + w) * 1024;
  bf16x8 aKtv[2];
#pragma unroll
  for (int mt = 0; mt < 2; ++mt)
#pragma unroll
    for (int j = 0; j < 8; ++j)
      aKtv[mt][j] = (__bf16)ktvH[(quad * 8 + j) * 32 + mt * 16 + l15];

  // ksum for the in-register Z: lane needs e = w*32 + quad*8 + j
  float ksum8[8];
#pragma unroll
  for (int j = 0; j < 8; ++j)
    ksum8[j] = ksumWs[s * 128 + w * 32 + quad * 8 + j];

  // Wo fragments (A-operand for orientation-2 GEMM3) + per-lane bias
  bf16x8 woF[2][4];
  float borr[2][4];
#pragma unroll
  for (int nt = 0; nt < 2; ++nt) {
    const int n = w * 32 + nt * 16 + l15;
#pragma unroll
    for (int kk = 0; kk < 4; ++kk)
      woF[nt][kk] = loadWfrag(Wo, kk * 32 + quad * 8, n);
#pragma unroll
    for (int r = 0; r < 4; ++r)
      borr[nt][r] = bo[w * 32 + nt * 16 + quad * 4 + r];
  }

  for (int t = 0; t < 4; ++t) {
    const int tok0 = chunk * 256 + t * 64;

    // --- GEMM2 (orientation 2): D[e'][tok] = KtV_h-frag @ Q^T, scaled by Z.
    // qf[ntq] holds Q[tok0+ntq*16+l15][w*32+quad*8 .. +8]; Z in-register:
    // the fragment covers 8/32 head dims, shfl_xor over quads completes it.
#pragma unroll
    for (int ntq = 0; ntq < 4; ++ntq) {
      const bf16x8 bq8 = qf[ntq];
      float dot = 0.f;
#pragma unroll
      for (int j = 0; j < 8; ++j) dot += (float)bq8[j] * ksum8[j];
      dot += __shfl_xor(dot, 16);
      dot += __shfl_xor(dot, 32);
      const float z = 1.f / (dot + 1e-6f);
      f32x4 acc[2] = {};
      acc[0] = mfma16(aKtv[0], bq8, acc[0]);
      acc[1] = mfma16(aKtv[1], bq8, acc[1]);
#pragma unroll
      for (int mt = 0; mt < 2; ++mt) {
        bf16x4 a4;
#pragma unroll
        for (int r = 0; r < 4; ++r) a4[r] = (__bf16)(acc[mt][r] * z);
        *(bf16x4*)(&A2s[(ntq * 16 + l15) * 136 + w * 32 + mt * 16 + quad * 4]) = a4;
      }
    }
    __syncthreads();  // A2 complete across all heads

    // --- issue next tile's qf loads here: GEMM3's MFMA + stores cover them ---
    bf16x8 qn[4];
    if (t < 3) {
      const __bf16* Qn = Qc + (size_t)(t + 1) * 64 * 128;
#pragma unroll
      for (int ntq = 0; ntq < 4; ++ntq)
        qn[ntq] = *(const bf16x8*)(Qn + (size_t)(ntq * 16 + l15) * 128 + w * 32 + quad * 8);
    }

    // --- GEMM3 (orientation 2): D[n][tok] = Wo^T-frag @ A2^T + bo.
    // Lane holds 4 consecutive n at fixed token -> one float4 store each. ---
#pragma unroll
    for (int ntq = 0; ntq < 4; ++ntq) {
      f32x4 acc[2] = {};
#pragma unroll
      for (int kk = 0; kk < 4; ++kk) {
        const bf16x8 a2f = *(const bf16x8*)(&A2s[(ntq * 16 + l15) * 136 + kk * 32 + quad * 8]);
        acc[0] = mfma16(woF[0][kk], a2f, acc[0]);
        acc[1] = mfma16(woF[1][kk], a2f, acc[1]);
      }
      const int tok = tok0 + ntq * 16 + l15;
      float* orow = Out + ((size_t)s * 2048 + tok) * 128;
#pragma unroll
      for (int nt = 0; nt < 2; ++nt) {
        float4 o4;
        o4.x = acc[nt][0] + borr[nt][0];
        o4.y = acc[nt][1] + borr[nt][1];
        o4.z = acc[nt][2] + borr[nt][2];
        o4.w = acc[nt][3] + borr[nt][3];
        *(float4*)(orow + w * 32 + nt * 16 + quad * 4) = o4;
      }
    }
    __syncthreads();  // A2 consumed; next tile may overwrite

    if (t < 3) {
#pragma unroll
      for (int ntq = 0; ntq < 4; ++ntq) qf[ntq] = qn[ntq];
    }
  }
}

extern "C" void kernel_launch(void* const* d_in, const int* in_sizes, int n_in,
                              void* d_out, int out_size, void* d_ws, size_t ws_size,
                              hipStream_t stream) {
  const float* X  = (const float*)d_in[0];
  const float* Wq = (const float*)d_in[1];
  const float* bq = (const float*)d_in[2];
  const float* Wk = (const float*)d_in[3];
  const float* bk = (const float*)d_in[4];
  const float* Wv = (const float*)d_in[5];
  const float* bv = (const float*)d_in[6];
  const float* Wo = (const float*)d_in[7];
  const float* bo = (const float*)d_in[8];
  float* Out = (float*)d_out;

  // ws layout: Q bf16 [128][2048][128] | ktv fp32 [128][4][32][32] | ksum fp32 [128][128]
  const size_t Q_BYTES    = (size_t)128 * 2048 * 128 * 2;        // 64 MiB
  const size_t KTV_BYTES  = (size_t)128 * 4 * 32 * 32 * 4;       // 2 MiB
  const size_t KSUM_BYTES = (size_t)128 * 128 * 4;               // 64 KiB
  __bf16* Qws   = (__bf16*)d_ws;
  float* ktvWs  = (float*)((char*)d_ws + Q_BYTES);
  float* ksumWs = (float*)((char*)d_ws + Q_BYTES + KTV_BYTES);

  hipMemsetAsync((char*)d_ws + Q_BYTES, 0, KTV_BYTES + KSUM_BYTES, stream);

  qkv_ktv_kernel<<<dim3(512), dim3(256), 0, stream>>>(
      X, Wq, bq, Wk, bk, Wv, bv, Qws, ktvWs, ksumWs);
  attn_out_kernel<<<dim3(1024), dim3(256), 0, stream>>>(
      Qws, ktvWs, ksumWs, Wo, bo, Out);
}